// Round 2
// baseline (271.888 us; speedup 1.0000x reference)
//
#include <hip/hip_runtime.h>
#include <hip/hip_bf16.h>

#define Bdim 64
#define Tdim 2048
#define Fdim 256
#define TAIL 256      // truncated EMA window: 0.8^256 ~ 1e-25, far below fp32 noise
#define NCH 8
#define CHT 32        // TAIL / NCH

#define BM 64
#define ASTR 264      // LDS row stride in bf16: 528 B, 16-B aligned; ds b128 ops land on the
                      // 8-phase structural floor with even bank-quad distribution (no extra conflict)

typedef __bf16 bf16x8 __attribute__((ext_vector_type(8)));
typedef float f32x16 __attribute__((ext_vector_type(16)));
typedef unsigned short u16x8 __attribute__((ext_vector_type(8)));

__device__ __forceinline__ unsigned short bf16_rne(float f) {
  unsigned int u = __float_as_uint(f);
  u += 0x7FFFu + ((u >> 16) & 1u);
  return (unsigned short)(u >> 16);
}

// blocks 0..511: EMA partials part[c][b][f]; blocks 512..575: W [f][g] -> Wt [g][f] bf16
__global__ void prep(const float* __restrict__ x, const float* __restrict__ W,
                     unsigned short* __restrict__ Wt, float* __restrict__ part) {
  if (blockIdx.x >= 512) {
    int base = (blockIdx.x - 512) * 1024 + threadIdx.x * 4;
#pragma unroll
    for (int j = 0; j < 4; ++j) {
      int i = base + j;                 // i = g*256 + f
      int g = i >> 8, f = i & 255;
      Wt[i] = bf16_rne(W[f * Fdim + g]);
    }
    return;
  }
  int b = blockIdx.x & 63, c = blockIdx.x >> 6, f = threadIdx.x;
  int t0 = Tdim - TAIL + c * CHT;
  // w(t) = 0.2 * 0.8^(T-1-t); iterate upward multiplying by 1.25 (exact in fp32)
  float w = 0.2f * exp2f((float)(Tdim - 1 - t0) * -0.32192809488736235f);
  const float* xp = x + ((size_t)b * Tdim + t0) * Fdim + f;
  float s = 0.f;
#pragma unroll
  for (int j = 0; j < CHT; ++j) {
    s += w * xp[(size_t)j * Fdim];
    w *= 1.25f;
  }
  part[(c * Bdim + b) * Fdim + f] = s;
}

// out[row][n] = sum_k x[row][k]*W[k][n] + bias[n] + lastref[b][n]
// BM=64 rows/block, BN=256 (full, x read exactly once), BK=256 (one barrier round).
// A staged in LDS as bf16; B fragments read directly from L2 (Wt is 128 KB, hot).
__global__ __launch_bounds__(256, 3)
void gemm_fused(const float* __restrict__ x, const unsigned short* __restrict__ Wt,
                const float* __restrict__ bias, const float* __restrict__ part,
                float* __restrict__ out) {
  __shared__ unsigned short Abuf[BM * ASTR];

  const int tid = threadIdx.x;
  const int blk = blockIdx.x;            // 0..2047
  const int b = blk >> 5;                // 32 row-tiles per batch
  const size_t row0 = (size_t)blk * BM;

  const int wave = tid >> 6;             // wave covers output cols [wave*64, wave*64+64)
  const int lane = tid & 63;
  const int lm = lane & 31;
  const int half = lane >> 5;
  const int n0 = wave * 64 + lm;
  const int n1 = n0 + 32;

  // lastref + bias for this lane's two output columns (L2-resident, no barrier needed)
  float lb0 = bias[n0], lb1 = bias[n1];
#pragma unroll
  for (int c = 0; c < NCH; ++c) {
    lb0 += part[(c * Bdim + b) * Fdim + n0];
    lb1 += part[(c * Bdim + b) * Fdim + n1];
  }

  // stage A: thread -> row r = tid>>2, 64-float chunk c0 = (tid&3)*64.
  // Global: each wave reads 16 KB contiguous. LDS writes: even bank-quad spread.
  {
    const int r = tid >> 2;
    const int c0 = (tid & 3) * 64;
    const float4* src = (const float4*)&x[(row0 + r) * Fdim + c0];
#pragma unroll
    for (int i = 0; i < 8; ++i) {
      float4 v0 = src[2 * i];
      float4 v1 = src[2 * i + 1];
      u16x8 w;
      w[0] = bf16_rne(v0.x); w[1] = bf16_rne(v0.y);
      w[2] = bf16_rne(v0.z); w[3] = bf16_rne(v0.w);
      w[4] = bf16_rne(v1.x); w[5] = bf16_rne(v1.y);
      w[6] = bf16_rne(v1.z); w[7] = bf16_rne(v1.w);
      *(u16x8*)&Abuf[r * ASTR + c0 + i * 8] = w;
    }
  }
  __syncthreads();

  f32x16 acc[2][2] = {};                 // [m-subtile][n-subtile], 32x32 each
  const int ko = half * 8;               // k = 8*(lane>>5) + j within a 16-wide step

#pragma unroll 4
  for (int s = 0; s < 16; ++s) {
    const int kk = s * 16 + ko;
    bf16x8 a0 = *(const bf16x8*)&Abuf[lm * ASTR + kk];
    bf16x8 a1 = *(const bf16x8*)&Abuf[(32 + lm) * ASTR + kk];
    bf16x8 b0 = *(const bf16x8*)&Wt[(size_t)n0 * Fdim + kk];
    bf16x8 b1 = *(const bf16x8*)&Wt[(size_t)n1 * Fdim + kk];
    acc[0][0] = __builtin_amdgcn_mfma_f32_32x32x16_bf16(a0, b0, acc[0][0], 0, 0, 0);
    acc[0][1] = __builtin_amdgcn_mfma_f32_32x32x16_bf16(a0, b1, acc[0][1], 0, 0, 0);
    acc[1][0] = __builtin_amdgcn_mfma_f32_32x32x16_bf16(a1, b0, acc[1][0], 0, 0, 0);
    acc[1][1] = __builtin_amdgcn_mfma_f32_32x32x16_bf16(a1, b1, acc[1][1], 0, 0, 0);
  }

  // epilogue: C/D layout col=lane&31, row=(r&3)+8*(r>>2)+4*(lane>>5)  [m74/m101]
  float* op = out + row0 * Fdim;
  const int rbase = 4 * half;
#pragma unroll
  for (int i = 0; i < 2; ++i) {
#pragma unroll
    for (int j = 0; j < 2; ++j) {
      const int n = (j == 0) ? n0 : n1;
      const float lb = (j == 0) ? lb0 : lb1;
#pragma unroll
      for (int r = 0; r < 16; ++r) {
        int rowi = i * 32 + (r & 3) + 8 * (r >> 2) + rbase;
        op[(size_t)rowi * Fdim + n] = acc[i][j][r] + lb;
      }
    }
  }
}

extern "C" void kernel_launch(void* const* d_in, const int* in_sizes, int n_in,
                              void* d_out, int out_size, void* d_ws, size_t ws_size,
                              hipStream_t stream) {
  const float* x = (const float*)d_in[0];
  const float* W = (const float*)d_in[1];
  const float* bias = (const float*)d_in[2];
  float* out = (float*)d_out;

  unsigned short* Wt = (unsigned short*)d_ws;                                   // 128 KB
  float* part = (float*)((char*)d_ws + Fdim * Fdim * sizeof(unsigned short));   // 512 KB

  prep<<<576, 256, 0, stream>>>(x, W, Wt, part);
  gemm_fused<<<(Bdim * Tdim) / BM, 256, 0, stream>>>(x, Wt, bias, part, out);
}